// Round 24
// baseline (168.048 us; speedup 1.0000x reference)
//
#include <hip/hip_runtime.h>
#include <hip/hip_bf16.h>

typedef __bf16 bf16;
typedef __bf16 bf16x4 __attribute__((ext_vector_type(4)));
typedef __bf16 bf16x8 __attribute__((ext_vector_type(8)));
typedef float f32x4 __attribute__((ext_vector_type(4)));

static constexpr int Bn = 4, Sn = 2048, Dn = 1024, Hn = 16, HDn = 64;
static constexpr int Mn = Bn * Sn;  // 8192

__device__ __forceinline__ void gload_lds16(const void* g, void* l) {
  __builtin_amdgcn_global_load_lds(
      (const __attribute__((address_space(1))) unsigned int*)g,
      (__attribute__((address_space(3))) unsigned int*)l, 16, 0, 0);
}

struct alignas(8) B4 { bf16 e[4]; };

// ---------------- fused prep: x fp32->bf16 (blocks 0..4095) +
//                  W [K][N] fp32 -> Wt [N][K] bf16 (blocks 4096..5119) -------
__global__ void prep_kernel(const float* __restrict__ x, bf16* __restrict__ xb,
                            const float* __restrict__ W0, const float* __restrict__ W1,
                            const float* __restrict__ W2, const float* __restrict__ W3,
                            bf16* __restrict__ WtQKV, bf16* __restrict__ Wot) {
  const int bid = blockIdx.x;
  if (bid < 4096) {
    const int i = bid * 256 + threadIdx.x;  // 4096*256 == Mn*Dn/8 exactly
    const float4* p = reinterpret_cast<const float4*>(x) + (size_t)i * 2;
    float4 a = p[0], b = p[1];
    bf16x8 v;
    v[0] = (bf16)a.x; v[1] = (bf16)a.y; v[2] = (bf16)a.z; v[3] = (bf16)a.w;
    v[4] = (bf16)b.x; v[5] = (bf16)b.y; v[6] = (bf16)b.z; v[7] = (bf16)b.w;
    *(reinterpret_cast<bf16x8*>(xb) + i) = v;
    return;
  }
  __shared__ bf16 tile[64][65];
  const int rem = bid - 4096;
  const int which = rem >> 8;            // 0..3
  const int by = (rem & 255) >> 4;       // k-tile
  const int bx = rem & 15;               // n-tile
  const float* W = (which == 0) ? W0 : (which == 1) ? W1 : (which == 2) ? W2 : W3;
  bf16* out = (which < 3) ? (WtQKV + (size_t)which * 1024 * 1024) : Wot;
  const int k0 = by * 64, n0 = bx * 64;
  const int t = threadIdx.x;
  const int tr = t >> 4, tc = (t & 15) * 4;
#pragma unroll
  for (int rr = 0; rr < 4; ++rr) {
    const int row = rr * 16 + tr;
    float4 v = *reinterpret_cast<const float4*>(&W[(size_t)(k0 + row) * 1024 + n0 + tc]);
    tile[row][tc + 0] = (bf16)v.x; tile[row][tc + 1] = (bf16)v.y;
    tile[row][tc + 2] = (bf16)v.z; tile[row][tc + 3] = (bf16)v.w;
  }
  __syncthreads();
#pragma unroll
  for (int rr = 0; rr < 4; ++rr) {
    const int row = rr * 16 + tr;  // n index
    B4 o;
#pragma unroll
    for (int j = 0; j < 4; ++j) o.e[j] = tile[tc + j][row];
    *reinterpret_cast<B4*>(&out[(size_t)(n0 + row) * 1024 + k0 + tc]) = o;
  }
}

// ---------------- QKV GEMM: 256x128 tile, dbuf + counted vmcnt --------------
// 8 waves as 4M x 2N -> per-wave tile stays 64x64 (fragment offsets, inner
// MFMA body, and the MODE-0 scatter epilogue are verbatim from the verified
// 128^2 kernel). NEW: double-buffered 96KB LDS + r21-verified pipeline
// {issue 6 staging loads -> s_waitcnt vmcnt(6) -> s_barrier -> compute ->
// s_barrier}: a tile's loads get a FULL K-step to land instead of the
// 2-barrier drain (the ~66% non-MFMA time at the m97 ceiling).
// Grid 24x32 = 768 = exactly 3 rounds/CU at 1 block/CU; uniform duration.
// Q pre-scaled by 1/sqrt(64)*log2(e); V stored in PV-fragment key order.
__global__ __launch_bounds__(512, 2)
void gemm_qkv(const bf16* __restrict__ A, const bf16* __restrict__ Bt,
              bf16* __restrict__ Qo, bf16* __restrict__ Ko, bf16* __restrict__ Vto) {
  __shared__ bf16 Al[2][256 * 64];
  __shared__ bf16 Bl[2][128 * 64];
  const int tid = threadIdx.x;
  const int lane = tid & 63;
  const int wv = tid >> 6;          // 0..7
  const int wm = wv >> 1, wn = wv & 1;  // 4M x 2N
  const int lr = lane & 15, lg = lane >> 4;
  const int m0 = blockIdx.y * 256, n0 = blockIdx.x * 128;

  // staging: A 4 chunks/thread, B 2 chunks/thread (16B each), swizzled source
  int soffA[4];
  const bf16* srcA[4];
#pragma unroll
  for (int c = 0; c < 4; ++c) {
    const int elem = c * 4096 + tid * 8;
    const int row = elem >> 6;
    const int gs = ((elem >> 3) & 7) ^ (row & 7);
    soffA[c] = elem;
    srcA[c] = A + (size_t)(m0 + row) * 1024 + gs * 8;
  }
  int soffB[2];
  const bf16* srcB[2];
#pragma unroll
  for (int c = 0; c < 2; ++c) {
    const int elem = c * 4096 + tid * 8;
    const int row = elem >> 6;
    const int gs = ((elem >> 3) & 7) ^ (row & 7);
    soffB[c] = elem;
    srcB[c] = Bt + (size_t)(n0 + row) * 1024 + gs * 8;
  }

  // fragment offsets (per-wave 64x64 tile, verbatim geometry)
  int offA[8], offB[8];
#pragma unroll
  for (int kk = 0; kk < 2; ++kk)
#pragma unroll
    for (int i = 0; i < 4; ++i) {
      const int rowA = wm * 64 + i * 16 + lr;      // 0..255
      offA[kk * 4 + i] = rowA * 64 + (((kk * 4 + lg) ^ (rowA & 7)) << 3);
      const int rowB = wn * 64 + i * 16 + lr;      // 0..127
      offB[kk * 4 + i] = rowB * 64 + (((kk * 4 + lg) ^ (rowB & 7)) << 3);
    }

  f32x4 acc[4][4] = {};

  // prologue: stage K-tile 0 into buf 0
#pragma unroll
  for (int c = 0; c < 4; ++c) gload_lds16(srcA[c], (bf16*)&Al[0][0] + soffA[c]);
#pragma unroll
  for (int c = 0; c < 2; ++c) gload_lds16(srcB[c], (bf16*)&Bl[0][0] + soffB[c]);

  for (int ks = 0; ks < 16; ++ks) {
    const int cur = ks & 1;
    if (ks + 1 < 16) {  // prefetch next K-tile into other buffer
      const int kn = (ks + 1) * 64;
#pragma unroll
      for (int c = 0; c < 4; ++c) gload_lds16(srcA[c] + kn, (bf16*)&Al[cur ^ 1][0] + soffA[c]);
#pragma unroll
      for (int c = 0; c < 2; ++c) gload_lds16(srcB[c] + kn, (bf16*)&Bl[cur ^ 1][0] + soffB[c]);
      asm volatile("s_waitcnt vmcnt(6)" ::: "memory");  // K-tile ks's 6 loads landed
    } else {
      asm volatile("s_waitcnt vmcnt(0)" ::: "memory");
    }
    __builtin_amdgcn_s_barrier();  // A: all waves' tile-ks loads visible
    const bf16* AlF = Al[cur];
    const bf16* BlF = Bl[cur];
#pragma unroll
    for (int kk = 0; kk < 2; ++kk) {
      bf16x8 af[4], bfr[4];
#pragma unroll
      for (int i = 0; i < 4; ++i) {
        af[i] = *reinterpret_cast<const bf16x8*>(AlF + offA[kk * 4 + i]);
        bfr[i] = *reinterpret_cast<const bf16x8*>(BlF + offB[kk * 4 + i]);
      }
      __builtin_amdgcn_s_setprio(1);
#pragma unroll
      for (int mi = 0; mi < 4; ++mi)
#pragma unroll
        for (int ni = 0; ni < 4; ++ni)
          acc[mi][ni] = __builtin_amdgcn_mfma_f32_16x16x32_bf16(af[mi], bfr[ni], acc[mi][ni], 0, 0, 0);
      __builtin_amdgcn_s_setprio(0);
    }
    __builtin_amdgcn_s_barrier();  // B: buffer reads done before next prefetch
  }

  // MODE-0 scatter epilogue (verbatim; wm now 0..3 within BM=256)
  const int mrow = lg * 4;
  const int w = n0 >> 10;
  const int nl0 = n0 & 1023;
  if (w == 2) {
    const int b = m0 >> 11;
    const int sBase = (m0 & 2047) + wm * 64 + lg * 8;  // permuted: 8a
#pragma unroll
    for (int ni = 0; ni < 4; ++ni) {
      const int nl = nl0 + wn * 64 + ni * 16 + lr;
      const int h = nl >> 6, hd = nl & 63;
      bf16* vbase = Vto + ((size_t)(b * 16 + h) * 64 + hd) * 2048;
#pragma unroll
      for (int mi = 0; mi < 4; ++mi) {
        B4 o;
#pragma unroll
        for (int i = 0; i < 4; ++i) o.e[i] = (bf16)acc[mi][ni][i];
        const int sNew = sBase + ((mi >> 1) << 5) + ((mi & 1) << 2);
        *reinterpret_cast<B4*>(&vbase[sNew]) = o;
      }
    }
  } else {
    const float fs = (w == 0) ? 0.18033688011112042f : 1.0f;
#pragma unroll
    for (int ni = 0; ni < 4; ++ni) {
      const int nl = nl0 + wn * 64 + ni * 16 + lr;
      const int h = nl >> 6, hd = nl & 63;
      bf16* dst = (w == 0) ? Qo : Ko;
#pragma unroll
      for (int mi = 0; mi < 4; ++mi) {
#pragma unroll
        for (int i = 0; i < 4; ++i) {
          const int m_g = m0 + wm * 64 + mi * 16 + mrow + i;
          const int b = m_g >> 11, s = m_g & 2047;
          dst[((size_t)(b * 16 + h) * 2048 + s) * 64 + hd] = (bf16)(acc[mi][ni][i] * fs);
        }
      }
    }
  }
}

// ---------------- out-proj GEMM: m97 single-buffer 128^2 (verified) ---------
__global__ __launch_bounds__(256, 4)
void gemm_out(const bf16* __restrict__ A, const bf16* __restrict__ Bt,
              float* __restrict__ Co, const float* __restrict__ bias) {
  __shared__ bf16 Al[128 * 64];
  __shared__ bf16 Bl[128 * 64];
  const int tid = threadIdx.x;
  const int lane = tid & 63;
  const int wv = tid >> 6;
  const int wm = wv >> 1, wn = wv & 1;
  const int lr = lane & 15, lg = lane >> 4;
  const int m0 = blockIdx.y * 128, n0 = blockIdx.x * 128;

  int soff[4];
  const bf16* srcA[4];
  const bf16* srcB[4];
#pragma unroll
  for (int it = 0; it < 4; ++it) {
    const int elem = it * 2048 + tid * 8;
    const int row = elem >> 6;
    const int g = (elem >> 3) & 7;
    const int gs = g ^ (row & 7);
    soff[it] = elem;
    srcA[it] = A + (size_t)(m0 + row) * 1024 + gs * 8;
    srcB[it] = Bt + (size_t)(n0 + row) * 1024 + gs * 8;
  }

  int offA[8], offB[8];
#pragma unroll
  for (int kk = 0; kk < 2; ++kk)
#pragma unroll
    for (int i = 0; i < 4; ++i) {
      const int rowA = wm * 64 + i * 16 + lr;
      offA[kk * 4 + i] = rowA * 64 + (((kk * 4 + lg) ^ (rowA & 7)) << 3);
      const int rowB = wn * 64 + i * 16 + lr;
      offB[kk * 4 + i] = rowB * 64 + (((kk * 4 + lg) ^ (rowB & 7)) << 3);
    }

  f32x4 acc[4][4] = {};

  for (int ks = 0; ks < 16; ++ks) {
    const int kn = ks * 64;
#pragma unroll
    for (int it = 0; it < 4; ++it) {
      gload_lds16(srcA[it] + kn, (bf16*)&Al[0] + soff[it]);
      gload_lds16(srcB[it] + kn, (bf16*)&Bl[0] + soff[it]);
    }
    __syncthreads();
#pragma unroll
    for (int kk = 0; kk < 2; ++kk) {
      bf16x8 af[4], bfr[4];
#pragma unroll
      for (int i = 0; i < 4; ++i) {
        af[i] = *reinterpret_cast<const bf16x8*>(Al + offA[kk * 4 + i]);
        bfr[i] = *reinterpret_cast<const bf16x8*>(Bl + offB[kk * 4 + i]);
      }
#pragma unroll
      for (int mi = 0; mi < 4; ++mi)
#pragma unroll
        for (int ni = 0; ni < 4; ++ni)
          acc[mi][ni] = __builtin_amdgcn_mfma_f32_16x16x32_bf16(af[mi], bfr[ni], acc[mi][ni], 0, 0, 0);
    }
    __syncthreads();
  }

  const int mrow = lg * 4;
#pragma unroll
  for (int ni = 0; ni < 4; ++ni) {
    const int n_g = n0 + wn * 64 + ni * 16 + lr;
    const float bv = bias[n_g];
#pragma unroll
    for (int mi = 0; mi < 4; ++mi) {
#pragma unroll
      for (int i = 0; i < 4; ++i) {
        const int m_g = m0 + wm * 64 + mi * 16 + mrow + i;
        Co[(size_t)m_g * 1024 + n_g] = acc[mi][ni][i] + bv;
      }
    }
  }
}

// ---------------- causal flash attention (r21 best: 63us, unchanged) --------
// Balanced two-phase shell + T1 XCD remap + dbuf prefetch + counted vmcnt +
// static-max softmax + pi-retimed PV + O^T epilogue.
__device__ __forceinline__ unsigned int pack2(float lo, float hi) {
  union { bf16 bb[2]; unsigned int u; } c;
  c.bb[0] = (bf16)lo; c.bb[1] = (bf16)hi;
  return c.u;
}

// static-max softmax + pack (round-9 verified indices).
// sc[ni][r] = S[q=qrow][key = kv0 + ni*16 + lg*4 + r]
template <bool DOMASK>
__device__ __forceinline__ float smax_pack(const f32x4 (&sc)[4], unsigned int (&pk)[4][2],
                                           int kv0, int qrow, int lg) {
  float p[4][4];
  float rs = 0.f;
#pragma unroll
  for (int ni = 0; ni < 4; ++ni)
#pragma unroll
    for (int r = 0; r < 4; ++r) {
      float pv = __builtin_amdgcn_exp2f(sc[ni][r]);
      if (DOMASK && (kv0 + ni * 16 + lg * 4 + r > qrow)) pv = 0.f;
      p[ni][r] = pv;
      rs += pv;
    }
#pragma unroll
  for (int ni = 0; ni < 4; ++ni)
#pragma unroll
    for (int tt = 0; tt < 2; ++tt)
      pk[ni][tt] = pack2(p[ni][2 * tt], p[ni][2 * tt + 1]);
  return rs;
}

__global__ __launch_bounds__(256, 4)
void attn_kernel(const bf16* __restrict__ Q, const bf16* __restrict__ K,
                 const bf16* __restrict__ Vt, bf16* __restrict__ ctx) {
  __shared__ bf16 Kl[2][4096];
  __shared__ bf16 Vl[2][4096];
  const int tid = threadIdx.x, lane = tid & 63, wv = tid >> 6;
  const int lr = lane & 15, lg = lane >> 4, lk = lg * 8;
  // XCD-aware remap (bijection over 1024 blocks)
  const int bid = blockIdx.x;
  const int xcd = bid & 7, slot = bid >> 3;
  const int bh = xcd * 8 + (slot >> 4);
  const int pi = slot & 15;
  const bf16* Qh = Q + (size_t)bh * Sn * 64;
  const bf16* Kh = K + (size_t)bh * Sn * 64;
  const bf16* Vh = Vt + (size_t)bh * 64 * (size_t)Sn;
  const int b = bh >> 4, h = bh & 15;

  const int e0 = tid * 8, e1 = 2048 + tid * 8;
  const int r0 = e0 >> 6, r1 = e1 >> 6;
  const int gs0 = ((e0 >> 3) & 7) ^ (r0 & 7), gs1 = ((e1 >> 3) & 7) ^ (r1 & 7);
  const bf16* srcK0 = Kh + r0 * 64 + gs0 * 8;
  const bf16* srcK1 = Kh + r1 * 64 + gs1 * 8;
  const bf16* srcV0 = Vh + (size_t)r0 * Sn + gs0 * 8;
  const bf16* srcV1 = Vh + (size_t)r1 * Sn + gs1 * 8;

  // fragment offsets (identical for K and V reads; loop-invariant)
  int offs[8];
#pragma unroll
  for (int kk = 0; kk < 2; ++kk)
#pragma unroll
    for (int ni = 0; ni < 4; ++ni) {
      const int row = ni * 16 + lr;
      offs[kk * 4 + ni] = row * 64 + (((kk * 4 + lg) ^ (row & 7)) << 3);
    }

  for (int ph = 0; ph < 2; ++ph) {
    const int qtile = ph ? pi : 31 - pi;
    const int qw = qtile * 64 + wv * 16;
    const int qrow = qw + lr;
    bf16x8 aq[2];
#pragma unroll
    for (int kk = 0; kk < 2; ++kk)
      aq[kk] = *reinterpret_cast<const bf16x8*>(&Qh[(size_t)(qw + lr) * 64 + kk * 32 + lk]);

    f32x4 acc[4] = {};
    float lstp = 0.f;  // per-lane partial row-sum (reduced once at epilogue)
    const int nt = qtile + 1;

    // prologue: stage kv-tile 0 into buf 0 (wait happens inside the loop)
    gload_lds16(srcK0, &Kl[0][e0]);
    gload_lds16(srcK1, &Kl[0][e1]);
    gload_lds16(srcV0, &Vl[0][e0]);
    gload_lds16(srcV1, &Vl[0][e1]);

    // incremental prefetch source pointers (tile 1 onward)
    const bf16* pK0 = srcK0 + 4096;
    const bf16* pK1 = srcK1 + 4096;
    const bf16* pV0 = srcV0 + 64;
    const bf16* pV1 = srcV1 + 64;

    for (int t = 0; t < nt; ++t) {
      const int cur = t & 1;
      if (t + 1 < nt) {  // prefetch next kv tile into other buffer
        gload_lds16(pK0, &Kl[cur ^ 1][e0]);
        gload_lds16(pK1, &Kl[cur ^ 1][e1]);
        gload_lds16(pV0, &Vl[cur ^ 1][e0]);
        gload_lds16(pV1, &Vl[cur ^ 1][e1]);
        pK0 += 4096; pK1 += 4096; pV0 += 64; pV1 += 64;
        asm volatile("s_waitcnt vmcnt(4)" ::: "memory");  // tile-t loads landed
      } else {
        asm volatile("s_waitcnt vmcnt(0)" ::: "memory");
      }
      __builtin_amdgcn_s_barrier();  // A: all waves' tile-t loads visible
      const int kv0 = t * 64;
      const bf16* KlF = Kl[cur];
      const bf16* VlF = Vl[cur];

      // QK^T (swapped): sc[ni] covers keys kv0 + ni*16 + lane-group offsets
      f32x4 sc[4] = {};
#pragma unroll
      for (int kk = 0; kk < 2; ++kk) {
        bf16x8 ak[4];
#pragma unroll
        for (int ni = 0; ni < 4; ++ni)
          ak[ni] = *reinterpret_cast<const bf16x8*>(KlF + offs[kk * 4 + ni]);
        __builtin_amdgcn_s_setprio(1);
#pragma unroll
        for (int ni = 0; ni < 4; ++ni)
          sc[ni] = __builtin_amdgcn_mfma_f32_16x16x32_bf16(ak[ni], aq[kk], sc[ni], 0, 0, 0);
        __builtin_amdgcn_s_setprio(0);
      }
      // softmax + pack (mask only on the last tile; uniform branch)
      unsigned int pk[4][2];
      if (t == nt - 1)
        lstp += smax_pack<true>(sc, pk, kv0, qrow, lg);
      else
        lstp += smax_pack<false>(sc, pk, kv0, qrow, lg);
      // PV (pi-retimed k order, single b128 V fragments)
#pragma unroll
      for (int kk = 0; kk < 2; ++kk) {
        union { unsigned int u[4]; bf16x8 v; } ap;
#pragma unroll
        for (int w = 0; w < 4; ++w) ap.u[w] = pk[2 * kk + (w >> 1)][w & 1];
        __builtin_amdgcn_s_setprio(1);
#pragma unroll
        for (int ni = 0; ni < 4; ++ni) {
          bf16x8 av = *reinterpret_cast<const bf16x8*>(VlF + offs[kk * 4 + ni]);
          acc[ni] = __builtin_amdgcn_mfma_f32_16x16x32_bf16(av, ap.v, acc[ni], 0, 0, 0);
        }
        __builtin_amdgcn_s_setprio(0);
      }
      __builtin_amdgcn_s_barrier();  // B: buffer reads done before next prefetch
    }

    // epilogue: reduce lst across the 4 lanes holding this q-row, then store
    // O^T -> lane holds O[q = qw+lr][hd = ni*16 + lg*4 + r]
    float lt = lstp;
    lt += __shfl_xor(lt, 16);
    lt += __shfl_xor(lt, 32);
    const float inv = 1.f / lt;
    bf16* cbase = ctx + (((size_t)b * Sn + qw + lr) * 16 + h) * 64;
#pragma unroll
    for (int ni = 0; ni < 4; ++ni) {
      B4 o;
#pragma unroll
      for (int r = 0; r < 4; ++r) o.e[r] = (bf16)(acc[ni][r] * inv);
      *reinterpret_cast<B4*>(cbase + ni * 16 + lg * 4) = o;
    }
    __syncthreads();  // phase boundary: all reads of bufs done before restage
  }
}

// ---------------- launch ----------------
extern "C" void kernel_launch(void* const* d_in, const int* in_sizes, int n_in,
                              void* d_out, int out_size, void* d_ws, size_t ws_size,
                              hipStream_t stream) {
  const float* x = (const float*)d_in[0];
  const float* Wq = (const float*)d_in[1];
  const float* Wk = (const float*)d_in[2];
  const float* Wv = (const float*)d_in[3];
  const float* Wo = (const float*)d_in[4];
  const float* bo = (const float*)d_in[5];

  char* ws = (char*)d_ws;
  bf16* xb    = (bf16*)(ws);                       // 16 MiB (reused as ctx later)
  bf16* WtQKV = (bf16*)(ws + 0x1000000);           // 6 MiB
  bf16* Wot   = (bf16*)(ws + 0x1600000);           // 2 MiB
  bf16* Qb    = (bf16*)(ws + 0x1800000);           // 16 MiB
  bf16* Kb    = (bf16*)(ws + 0x2800000);           // 16 MiB
  bf16* Vtb   = (bf16*)(ws + 0x3800000);           // 16 MiB  (end: 72 MiB)
  bf16* ctx   = xb;                                // alias: xb dead after QKV GEMM

  prep_kernel<<<dim3(5120), dim3(256), 0, stream>>>(x, xb, Wq, Wk, Wv, Wo, WtQKV, Wot);
  gemm_qkv<<<dim3(24, 32), dim3(512), 0, stream>>>(xb, WtQKV, Qb, Kb, Vtb);
  attn_kernel<<<dim3(1024), dim3(256), 0, stream>>>(Qb, Kb, Vtb, ctx);
  gemm_out<<<dim3(8, 64), dim3(256), 0, stream>>>(ctx, Wot, (float*)d_out, bo);
}

// Round 25
// 155.337 us; speedup vs baseline: 1.0818x; 1.0818x over previous
//
#include <hip/hip_runtime.h>
#include <hip/hip_bf16.h>

typedef __bf16 bf16;
typedef __bf16 bf16x4 __attribute__((ext_vector_type(4)));
typedef __bf16 bf16x8 __attribute__((ext_vector_type(8)));
typedef float f32x4 __attribute__((ext_vector_type(4)));

static constexpr int Bn = 4, Sn = 2048, Dn = 1024, Hn = 16, HDn = 64;
static constexpr int Mn = Bn * Sn;  // 8192

__device__ __forceinline__ void gload_lds16(const void* g, void* l) {
  __builtin_amdgcn_global_load_lds(
      (const __attribute__((address_space(1))) unsigned int*)g,
      (__attribute__((address_space(3))) unsigned int*)l, 16, 0, 0);
}

struct alignas(8) B4 { bf16 e[4]; };

// ---------------- fused prep: x fp32->bf16 (blocks 0..4095) +
//                  W [K][N] fp32 -> Wt [N][K] bf16 (blocks 4096..5119) -------
__global__ void prep_kernel(const float* __restrict__ x, bf16* __restrict__ xb,
                            const float* __restrict__ W0, const float* __restrict__ W1,
                            const float* __restrict__ W2, const float* __restrict__ W3,
                            bf16* __restrict__ WtQKV, bf16* __restrict__ Wot) {
  const int bid = blockIdx.x;
  if (bid < 4096) {
    const int i = bid * 256 + threadIdx.x;  // 4096*256 == Mn*Dn/8 exactly
    const float4* p = reinterpret_cast<const float4*>(x) + (size_t)i * 2;
    float4 a = p[0], b = p[1];
    bf16x8 v;
    v[0] = (bf16)a.x; v[1] = (bf16)a.y; v[2] = (bf16)a.z; v[3] = (bf16)a.w;
    v[4] = (bf16)b.x; v[5] = (bf16)b.y; v[6] = (bf16)b.z; v[7] = (bf16)b.w;
    *(reinterpret_cast<bf16x8*>(xb) + i) = v;
    return;
  }
  __shared__ bf16 tile[64][65];
  const int rem = bid - 4096;
  const int which = rem >> 8;            // 0..3
  const int by = (rem & 255) >> 4;       // k-tile
  const int bx = rem & 15;               // n-tile
  const float* W = (which == 0) ? W0 : (which == 1) ? W1 : (which == 2) ? W2 : W3;
  bf16* out = (which < 3) ? (WtQKV + (size_t)which * 1024 * 1024) : Wot;
  const int k0 = by * 64, n0 = bx * 64;
  const int t = threadIdx.x;
  const int tr = t >> 4, tc = (t & 15) * 4;
#pragma unroll
  for (int rr = 0; rr < 4; ++rr) {
    const int row = rr * 16 + tr;
    float4 v = *reinterpret_cast<const float4*>(&W[(size_t)(k0 + row) * 1024 + n0 + tc]);
    tile[row][tc + 0] = (bf16)v.x; tile[row][tc + 1] = (bf16)v.y;
    tile[row][tc + 2] = (bf16)v.z; tile[row][tc + 3] = (bf16)v.w;
  }
  __syncthreads();
#pragma unroll
  for (int rr = 0; rr < 4; ++rr) {
    const int row = rr * 16 + tr;  // n index
    B4 o;
#pragma unroll
    for (int j = 0; j < 4; ++j) o.e[j] = tile[tc + j][row];
    *reinterpret_cast<B4*>(&out[(size_t)(n0 + row) * 1024 + k0 + tc]) = o;
  }
}

// ---------------- GEMM: C[M][N] = A[M][1024] @ Bt[N][1024]^T ----------------
// m97 single-buffer structure (32 KB LDS -> 4 blocks/CU). Verified optimum
// across: 5-block bounds (r22: VGPR spill, 4x slower), 64KB dbuf (r14: 2
// blocks/CU, -20%), 96KB dbuf 256x128 (r24: 1 block/CU, -30%).
// T2 XOR-swizzled LDS via pre-swizzled global source; global_load_lds w=16.
// MODE 0: Q pre-scaled by 1/sqrt(64)*log2(e); V stored in PV-fragment key
// order: key 32K+16c+4a+b -> position 32K+8a+4c+b (a=lg, b=i, c=mi&1).
template <int MODE>
__global__ __launch_bounds__(256, 4)
void gemm_kernel(const bf16* __restrict__ A, const bf16* __restrict__ Bt,
                 float* __restrict__ Co, const float* __restrict__ bias,
                 bf16* __restrict__ Qo, bf16* __restrict__ Ko, bf16* __restrict__ Vto) {
  __shared__ bf16 Al[128 * 64];
  __shared__ bf16 Bl[128 * 64];
  const int tid = threadIdx.x;
  const int lane = tid & 63;
  const int wv = tid >> 6;
  const int wm = wv >> 1, wn = wv & 1;
  const int lr = lane & 15, lg = lane >> 4;
  const int m0 = blockIdx.y * 128, n0 = blockIdx.x * 128;

  int soff[4];
  const bf16* srcA[4];
  const bf16* srcB[4];
#pragma unroll
  for (int it = 0; it < 4; ++it) {
    const int elem = it * 2048 + tid * 8;
    const int row = elem >> 6;
    const int g = (elem >> 3) & 7;
    const int gs = g ^ (row & 7);
    soff[it] = elem;
    srcA[it] = A + (size_t)(m0 + row) * 1024 + gs * 8;
    srcB[it] = Bt + (size_t)(n0 + row) * 1024 + gs * 8;
  }

  int offA[8], offB[8];
#pragma unroll
  for (int kk = 0; kk < 2; ++kk)
#pragma unroll
    for (int i = 0; i < 4; ++i) {
      const int rowA = wm * 64 + i * 16 + lr;
      offA[kk * 4 + i] = rowA * 64 + (((kk * 4 + lg) ^ (rowA & 7)) << 3);
      const int rowB = wn * 64 + i * 16 + lr;
      offB[kk * 4 + i] = rowB * 64 + (((kk * 4 + lg) ^ (rowB & 7)) << 3);
    }

  f32x4 acc[4][4] = {};

  for (int ks = 0; ks < 16; ++ks) {
    const int kn = ks * 64;
#pragma unroll
    for (int it = 0; it < 4; ++it) {
      gload_lds16(srcA[it] + kn, (bf16*)&Al[0] + soff[it]);
      gload_lds16(srcB[it] + kn, (bf16*)&Bl[0] + soff[it]);
    }
    __syncthreads();
#pragma unroll
    for (int kk = 0; kk < 2; ++kk) {
      bf16x8 af[4], bfr[4];
#pragma unroll
      for (int i = 0; i < 4; ++i) {
        af[i] = *reinterpret_cast<const bf16x8*>(Al + offA[kk * 4 + i]);
        bfr[i] = *reinterpret_cast<const bf16x8*>(Bl + offB[kk * 4 + i]);
      }
#pragma unroll
      for (int mi = 0; mi < 4; ++mi)
#pragma unroll
        for (int ni = 0; ni < 4; ++ni)
          acc[mi][ni] = __builtin_amdgcn_mfma_f32_16x16x32_bf16(af[mi], bfr[ni], acc[mi][ni], 0, 0, 0);
    }
    __syncthreads();
  }

  const int mrow = lg * 4;
  if (MODE == 0) {
    const int w = n0 >> 10;
    const int nl0 = n0 & 1023;
    if (w == 2) {
      const int b = m0 >> 11;
      const int sBase = (m0 & 2047) + wm * 64 + lg * 8;  // permuted: 8a
#pragma unroll
      for (int ni = 0; ni < 4; ++ni) {
        const int nl = nl0 + wn * 64 + ni * 16 + lr;
        const int h = nl >> 6, hd = nl & 63;
        bf16* vbase = Vto + ((size_t)(b * 16 + h) * 64 + hd) * 2048;
#pragma unroll
        for (int mi = 0; mi < 4; ++mi) {
          B4 o;
#pragma unroll
          for (int i = 0; i < 4; ++i) o.e[i] = (bf16)acc[mi][ni][i];
          const int sNew = sBase + ((mi >> 1) << 5) + ((mi & 1) << 2);
          *reinterpret_cast<B4*>(&vbase[sNew]) = o;
        }
      }
    } else {
      const float fs = (w == 0) ? 0.18033688011112042f : 1.0f;
#pragma unroll
      for (int ni = 0; ni < 4; ++ni) {
        const int nl = nl0 + wn * 64 + ni * 16 + lr;
        const int h = nl >> 6, hd = nl & 63;
        bf16* dst = (w == 0) ? Qo : Ko;
#pragma unroll
        for (int mi = 0; mi < 4; ++mi) {
#pragma unroll
          for (int i = 0; i < 4; ++i) {
            const int m_g = m0 + wm * 64 + mi * 16 + mrow + i;
            const int b = m_g >> 11, s = m_g & 2047;
            dst[((size_t)(b * 16 + h) * 2048 + s) * 64 + hd] = (bf16)(acc[mi][ni][i] * fs);
          }
        }
      }
    }
  } else {
#pragma unroll
    for (int ni = 0; ni < 4; ++ni) {
      const int n_g = n0 + wn * 64 + ni * 16 + lr;
      const float bv = bias[n_g];
#pragma unroll
      for (int mi = 0; mi < 4; ++mi) {
#pragma unroll
        for (int i = 0; i < 4; ++i) {
          const int m_g = m0 + wm * 64 + mi * 16 + mrow + i;
          Co[(size_t)m_g * 1024 + n_g] = acc[mi][ni][i] + bv;
        }
      }
    }
  }
}

// ---------------- causal flash attention (verified best: ~63us) -------------
// Balanced two-phase shell + T1 XCD remap + dbuf prefetch + counted vmcnt +
// static-max softmax + pi-retimed PV + O^T epilogue.
__device__ __forceinline__ unsigned int pack2(float lo, float hi) {
  union { bf16 bb[2]; unsigned int u; } c;
  c.bb[0] = (bf16)lo; c.bb[1] = (bf16)hi;
  return c.u;
}

// static-max softmax + pack (round-9 verified indices).
// sc[ni][r] = S[q=qrow][key = kv0 + ni*16 + lg*4 + r]
template <bool DOMASK>
__device__ __forceinline__ float smax_pack(const f32x4 (&sc)[4], unsigned int (&pk)[4][2],
                                           int kv0, int qrow, int lg) {
  float p[4][4];
  float rs = 0.f;
#pragma unroll
  for (int ni = 0; ni < 4; ++ni)
#pragma unroll
    for (int r = 0; r < 4; ++r) {
      float pv = __builtin_amdgcn_exp2f(sc[ni][r]);
      if (DOMASK && (kv0 + ni * 16 + lg * 4 + r > qrow)) pv = 0.f;
      p[ni][r] = pv;
      rs += pv;
    }
#pragma unroll
  for (int ni = 0; ni < 4; ++ni)
#pragma unroll
    for (int tt = 0; tt < 2; ++tt)
      pk[ni][tt] = pack2(p[ni][2 * tt], p[ni][2 * tt + 1]);
  return rs;
}

__global__ __launch_bounds__(256, 4)
void attn_kernel(const bf16* __restrict__ Q, const bf16* __restrict__ K,
                 const bf16* __restrict__ Vt, bf16* __restrict__ ctx) {
  __shared__ bf16 Kl[2][4096];
  __shared__ bf16 Vl[2][4096];
  const int tid = threadIdx.x, lane = tid & 63, wv = tid >> 6;
  const int lr = lane & 15, lg = lane >> 4, lk = lg * 8;
  // XCD-aware remap (bijection over 1024 blocks)
  const int bid = blockIdx.x;
  const int xcd = bid & 7, slot = bid >> 3;
  const int bh = xcd * 8 + (slot >> 4);
  const int pi = slot & 15;
  const bf16* Qh = Q + (size_t)bh * Sn * 64;
  const bf16* Kh = K + (size_t)bh * Sn * 64;
  const bf16* Vh = Vt + (size_t)bh * 64 * (size_t)Sn;
  const int b = bh >> 4, h = bh & 15;

  const int e0 = tid * 8, e1 = 2048 + tid * 8;
  const int r0 = e0 >> 6, r1 = e1 >> 6;
  const int gs0 = ((e0 >> 3) & 7) ^ (r0 & 7), gs1 = ((e1 >> 3) & 7) ^ (r1 & 7);
  const bf16* srcK0 = Kh + r0 * 64 + gs0 * 8;
  const bf16* srcK1 = Kh + r1 * 64 + gs1 * 8;
  const bf16* srcV0 = Vh + (size_t)r0 * Sn + gs0 * 8;
  const bf16* srcV1 = Vh + (size_t)r1 * Sn + gs1 * 8;

  // fragment offsets (identical for K and V reads; loop-invariant)
  int offs[8];
#pragma unroll
  for (int kk = 0; kk < 2; ++kk)
#pragma unroll
    for (int ni = 0; ni < 4; ++ni) {
      const int row = ni * 16 + lr;
      offs[kk * 4 + ni] = row * 64 + (((kk * 4 + lg) ^ (row & 7)) << 3);
    }

  for (int ph = 0; ph < 2; ++ph) {
    const int qtile = ph ? pi : 31 - pi;
    const int qw = qtile * 64 + wv * 16;
    const int qrow = qw + lr;
    bf16x8 aq[2];
#pragma unroll
    for (int kk = 0; kk < 2; ++kk)
      aq[kk] = *reinterpret_cast<const bf16x8*>(&Qh[(size_t)(qw + lr) * 64 + kk * 32 + lk]);

    f32x4 acc[4] = {};
    float lstp = 0.f;  // per-lane partial row-sum (reduced once at epilogue)
    const int nt = qtile + 1;

    // prologue: stage kv-tile 0 into buf 0 (wait happens inside the loop)
    gload_lds16(srcK0, &Kl[0][e0]);
    gload_lds16(srcK1, &Kl[0][e1]);
    gload_lds16(srcV0, &Vl[0][e0]);
    gload_lds16(srcV1, &Vl[0][e1]);

    // incremental prefetch source pointers (tile 1 onward)
    const bf16* pK0 = srcK0 + 4096;
    const bf16* pK1 = srcK1 + 4096;
    const bf16* pV0 = srcV0 + 64;
    const bf16* pV1 = srcV1 + 64;

    for (int t = 0; t < nt; ++t) {
      const int cur = t & 1;
      if (t + 1 < nt) {  // prefetch next kv tile into other buffer
        gload_lds16(pK0, &Kl[cur ^ 1][e0]);
        gload_lds16(pK1, &Kl[cur ^ 1][e1]);
        gload_lds16(pV0, &Vl[cur ^ 1][e0]);
        gload_lds16(pV1, &Vl[cur ^ 1][e1]);
        pK0 += 4096; pK1 += 4096; pV0 += 64; pV1 += 64;
        asm volatile("s_waitcnt vmcnt(4)" ::: "memory");  // tile-t loads landed
      } else {
        asm volatile("s_waitcnt vmcnt(0)" ::: "memory");
      }
      __builtin_amdgcn_s_barrier();  // A: all waves' tile-t loads visible
      const int kv0 = t * 64;
      const bf16* KlF = Kl[cur];
      const bf16* VlF = Vl[cur];

      // QK^T (swapped): sc[ni] covers keys kv0 + ni*16 + lane-group offsets
      f32x4 sc[4] = {};
#pragma unroll
      for (int kk = 0; kk < 2; ++kk) {
        bf16x8 ak[4];
#pragma unroll
        for (int ni = 0; ni < 4; ++ni)
          ak[ni] = *reinterpret_cast<const bf16x8*>(KlF + offs[kk * 4 + ni]);
        __builtin_amdgcn_s_setprio(1);
#pragma unroll
        for (int ni = 0; ni < 4; ++ni)
          sc[ni] = __builtin_amdgcn_mfma_f32_16x16x32_bf16(ak[ni], aq[kk], sc[ni], 0, 0, 0);
        __builtin_amdgcn_s_setprio(0);
      }
      // softmax + pack (mask only on the last tile; uniform branch)
      unsigned int pk[4][2];
      if (t == nt - 1)
        lstp += smax_pack<true>(sc, pk, kv0, qrow, lg);
      else
        lstp += smax_pack<false>(sc, pk, kv0, qrow, lg);
      // PV (pi-retimed k order, single b128 V fragments)
#pragma unroll
      for (int kk = 0; kk < 2; ++kk) {
        union { unsigned int u[4]; bf16x8 v; } ap;
#pragma unroll
        for (int w = 0; w < 4; ++w) ap.u[w] = pk[2 * kk + (w >> 1)][w & 1];
        __builtin_amdgcn_s_setprio(1);
#pragma unroll
        for (int ni = 0; ni < 4; ++ni) {
          bf16x8 av = *reinterpret_cast<const bf16x8*>(VlF + offs[kk * 4 + ni]);
          acc[ni] = __builtin_amdgcn_mfma_f32_16x16x32_bf16(av, ap.v, acc[ni], 0, 0, 0);
        }
        __builtin_amdgcn_s_setprio(0);
      }
      __builtin_amdgcn_s_barrier();  // B: buffer reads done before next prefetch
    }

    // epilogue: reduce lst across the 4 lanes holding this q-row, then store
    // O^T -> lane holds O[q = qw+lr][hd = ni*16 + lg*4 + r]
    float lt = lstp;
    lt += __shfl_xor(lt, 16);
    lt += __shfl_xor(lt, 32);
    const float inv = 1.f / lt;
    bf16* cbase = ctx + (((size_t)b * Sn + qw + lr) * 16 + h) * 64;
#pragma unroll
    for (int ni = 0; ni < 4; ++ni) {
      B4 o;
#pragma unroll
      for (int r = 0; r < 4; ++r) o.e[r] = (bf16)(acc[ni][r] * inv);
      *reinterpret_cast<B4*>(cbase + ni * 16 + lg * 4) = o;
    }
    __syncthreads();  // phase boundary: all reads of bufs done before restage
  }
}

// ---------------- launch ----------------
extern "C" void kernel_launch(void* const* d_in, const int* in_sizes, int n_in,
                              void* d_out, int out_size, void* d_ws, size_t ws_size,
                              hipStream_t stream) {
  const float* x = (const float*)d_in[0];
  const float* Wq = (const float*)d_in[1];
  const float* Wk = (const float*)d_in[2];
  const float* Wv = (const float*)d_in[3];
  const float* Wo = (const float*)d_in[4];
  const float* bo = (const float*)d_in[5];

  char* ws = (char*)d_ws;
  bf16* xb    = (bf16*)(ws);                       // 16 MiB (reused as ctx later)
  bf16* WtQKV = (bf16*)(ws + 0x1000000);           // 6 MiB
  bf16* Wot   = (bf16*)(ws + 0x1600000);           // 2 MiB
  bf16* Qb    = (bf16*)(ws + 0x1800000);           // 16 MiB
  bf16* Kb    = (bf16*)(ws + 0x2800000);           // 16 MiB
  bf16* Vtb   = (bf16*)(ws + 0x3800000);           // 16 MiB  (end: 72 MiB)
  bf16* ctx   = xb;                                // alias: xb dead after QKV GEMM

  prep_kernel<<<dim3(5120), dim3(256), 0, stream>>>(x, xb, Wq, Wk, Wv, Wo, WtQKV, Wot);
  gemm_kernel<0><<<dim3(24, 64), dim3(256), 0, stream>>>(xb, WtQKV, nullptr, nullptr, Qb, Kb, Vtb);
  attn_kernel<<<dim3(1024), dim3(256), 0, stream>>>(Qb, Kb, Vtb, ctx);
  gemm_kernel<1><<<dim3(8, 64), dim3(256), 0, stream>>>(ctx, Wot, (float*)d_out, bo,
                                                        nullptr, nullptr, nullptr);
}